// Round 8
// baseline (409.226 us; speedup 1.0000x reference)
//
#include <hip/hip_runtime.h>
#include <math.h>

typedef unsigned short u16;
typedef unsigned int u32;
typedef __attribute__((ext_vector_type(8))) short short8;
typedef __attribute__((ext_vector_type(4))) float f32x4;
typedef __attribute__((ext_vector_type(16))) float f32x16;

#define Bb 2
#define Tt 2048
#define Dd 2048
#define Hh 16
#define HDim 128
#define NQKV 6144
#define CEXP_VAL 0.127521410699097f   // (1/sqrt(128)) * log2(e)

__device__ __forceinline__ u16 f2b(float f) {
    u32 u = __float_as_uint(f);
    u32 r = (u + 0x7FFFu + ((u >> 16) & 1u)) >> 16;
    return (u16)r;
}
__device__ __forceinline__ float2 b2f2(u32 u) {
    return make_float2(__uint_as_float(u << 16), __uint_as_float(u & 0xFFFF0000u));
}
__device__ __forceinline__ u32 pack2(float a, float b) {
    return (u32)f2b(a) | ((u32)f2b(b) << 16);
}
// cheap round-half-up bf16 pair pack (positive finite inputs)
__device__ __forceinline__ u32 pack2rz(float a, float b) {
    u32 ua = __float_as_uint(a) + 0x8000u;
    u32 ub = __float_as_uint(b) + 0x8000u;
    return (ua >> 16) | (ub & 0xFFFF0000u);
}

// async global->LDS, 16B per lane; LDS dest = uniform base + lane*16 [m97/m104]
#define GLD16(g, l) __builtin_amdgcn_global_load_lds(                                   \
    (const __attribute__((address_space(1))) void*)(g),                                 \
    (__attribute__((address_space(3))) void*)(l), 16, 0, 0)

// ---------------- cast fp32 -> bf16 (vectorized) ----------------
__global__ __launch_bounds__(256) void cast_f32_bf16(const float* __restrict__ src,
                                                     u16* __restrict__ dst, int n) {
    int i = (blockIdx.x * 256 + threadIdx.x) * 4;
    if (i >= n) return;
    float4 v = *(const float4*)(src + i);
    *(uint2*)(dst + i) = make_uint2(pack2(v.x, v.y), pack2(v.z, v.w));
}

// ---------------- transpose fp32 [R][C] -> bf16 [C][R] ----------------
__global__ __launch_bounds__(256) void transpose_cast(const float* __restrict__ src,
                                                      u16* __restrict__ dst, int R, int C) {
    __shared__ float tile[32][33];
    int c0 = blockIdx.x << 5, r0 = blockIdx.y << 5;
    int tx = threadIdx.x & 31, ty = threadIdx.x >> 5;   // 32 x 8
    #pragma unroll
    for (int i = 0; i < 32; i += 8)
        tile[ty + i][tx] = src[(size_t)(r0 + ty + i) * C + c0 + tx];
    __syncthreads();
    #pragma unroll
    for (int i = 0; i < 32; i += 8)
        dst[(size_t)(c0 + ty + i) * R + r0 + tx] = f2b(tile[tx][ty + i]);
}

// ---------------- bf16 MFMA GEMM (m97 structure, single-buffer): qkv proj ----------------
// 128x128 tile, BK=64 as two [128][32] half-tiles. Scatter epilogue to planar q/k/v.
__global__ __launch_bounds__(256) void gemm_qkv(const u16* __restrict__ A, const u16* __restrict__ Bt,
                                                u16* __restrict__ Cv, int Mn, int Nn, int Kn) {
    __shared__ __align__(16) u16 As[2 * 4096];
    __shared__ __align__(16) u16 Bs[2 * 4096];
    const int tid = threadIdx.x;
    const int m0 = blockIdx.y << 7, n0 = blockIdx.x << 7;
    const int wave = tid >> 6, lane = tid & 63;
    const int wm = (wave >> 1) << 6, wn = (wave & 1) << 6;
    const int l15 = lane & 15, lq = lane >> 4;

    f32x4 acc[4][4];
    #pragma unroll
    for (int i = 0; i < 4; i++)
        #pragma unroll
        for (int j = 0; j < 4; j++)
            acc[i][j] = (f32x4){0.f, 0.f, 0.f, 0.f};

    const int srow = wave * 32 + (lane >> 2);
    const int scol = (lane & 3) << 3;
    const u16* ga = A + (size_t)(m0 + srow) * Kn + scol;
    const u16* gb = Bt + (size_t)(n0 + srow) * Kn + scol;
    u16* lA = &As[wave * 1024];
    u16* lB = &Bs[wave * 1024];

    for (int k0 = 0; k0 < Kn; k0 += 64) {
        __syncthreads();
        #pragma unroll
        for (int h = 0; h < 2; h++) {
            GLD16(ga + k0 + h * 32, lA + h * 4096);
            GLD16(ga + k0 + h * 32 + (size_t)16 * Kn, lA + h * 4096 + 512);
            GLD16(gb + k0 + h * 32, lB + h * 4096);
            GLD16(gb + k0 + h * 32 + (size_t)16 * Kn, lB + h * 4096 + 512);
        }
        __syncthreads();
        #pragma unroll
        for (int h = 0; h < 2; h++) {
            const u16* Ah = As + h * 4096;
            const u16* Bh = Bs + h * 4096;
            short8 a[4], b[4];
            #pragma unroll
            for (int i = 0; i < 4; i++) {
                a[i] = *(const short8*)&Ah[(wm + (i << 4) + l15) * 32 + lq * 8];
                b[i] = *(const short8*)&Bh[(wn + (i << 4) + l15) * 32 + lq * 8];
            }
            #pragma unroll
            for (int i = 0; i < 4; i++)
                #pragma unroll
                for (int j = 0; j < 4; j++)
                    acc[i][j] = __builtin_amdgcn_mfma_f32_16x16x32_bf16(a[i], b[j], acc[i][j], 0, 0, 0);
        }
    }

    // C/D layout: col = lane&15, row = (lane>>4)*4 + reg  [m89/m91]
    #pragma unroll
    for (int i = 0; i < 4; i++) {
        int mbase = m0 + wm + (i << 4) + (lq << 2);
        #pragma unroll
        for (int j = 0; j < 4; j++) {
            int n = n0 + wn + (j << 4) + l15;
            int f = n >> 7;
            int h = f / 3, sel = f - 3 * h;
            int d = n & 127;
            u16* base = Cv + (size_t)sel * 8388608;
            #pragma unroll
            for (int r = 0; r < 4; r++) {
                int m = mbase + r;
                int b = m >> 11, t = m & 2047;
                base[(((size_t)(b * 16 + h)) * 2048 + t) * 128 + d] = f2b(acc[i][j][r]);
            }
        }
    }
}

// ---------------- bf16 MFMA GEMM, double-buffered (for 2-blocks/CU grids) ----------------
// BK=64 ping-pong: issue next buffer's GLD16 right after the barrier, compute current.
// The barrier's forced vmcnt(0) then drains loads issued one full compute-phase ago.
__global__ __launch_bounds__(256, 2) void gemm_db(const u16* __restrict__ A, const u16* __restrict__ Bt,
                                                  float* __restrict__ Cv, int Mn, int Nn, int Kn) {
    __shared__ __align__(16) u16 As[2 * 8192];   // [buf][2 halves * 4096]
    __shared__ __align__(16) u16 Bs[2 * 8192];
    const int tid = threadIdx.x;
    const int m0 = blockIdx.y << 7, n0 = blockIdx.x << 7;
    const int wave = tid >> 6, lane = tid & 63;
    const int wm = (wave >> 1) << 6, wn = (wave & 1) << 6;
    const int l15 = lane & 15, lq = lane >> 4;

    f32x4 acc[4][4];
    #pragma unroll
    for (int i = 0; i < 4; i++)
        #pragma unroll
        for (int j = 0; j < 4; j++)
            acc[i][j] = (f32x4){0.f, 0.f, 0.f, 0.f};

    const int srow = wave * 32 + (lane >> 2);
    const int scol = (lane & 3) << 3;
    const u16* ga = A + (size_t)(m0 + srow) * Kn + scol;
    const u16* gb = Bt + (size_t)(n0 + srow) * Kn + scol;
    const int lofs = wave * 1024;

    // prologue: buffer 0 <- k0 = 0
    #pragma unroll
    for (int h = 0; h < 2; h++) {
        GLD16(ga + h * 32, &As[lofs + h * 4096]);
        GLD16(ga + h * 32 + (size_t)16 * Kn, &As[lofs + h * 4096 + 512]);
        GLD16(gb + h * 32, &Bs[lofs + h * 4096]);
        GLD16(gb + h * 32 + (size_t)16 * Kn, &Bs[lofs + h * 4096 + 512]);
    }

    for (int k0 = 0; k0 < Kn; k0 += 64) {
        const int cb = (k0 >> 6) & 1;
        const int nb = 1 - cb;
        __syncthreads();     // drains GLD16s for buf cb (issued last iter / prologue)
        if (k0 + 64 < Kn) {
            const int kn = k0 + 64;
            #pragma unroll
            for (int h = 0; h < 2; h++) {
                GLD16(ga + kn + h * 32, &As[nb * 8192 + lofs + h * 4096]);
                GLD16(ga + kn + h * 32 + (size_t)16 * Kn, &As[nb * 8192 + lofs + h * 4096 + 512]);
                GLD16(gb + kn + h * 32, &Bs[nb * 8192 + lofs + h * 4096]);
                GLD16(gb + kn + h * 32 + (size_t)16 * Kn, &Bs[nb * 8192 + lofs + h * 4096 + 512]);
            }
        }
        #pragma unroll
        for (int h = 0; h < 2; h++) {
            const u16* Ah = As + cb * 8192 + h * 4096;
            const u16* Bh = Bs + cb * 8192 + h * 4096;
            short8 a[4], b[4];
            #pragma unroll
            for (int i = 0; i < 4; i++) {
                a[i] = *(const short8*)&Ah[(wm + (i << 4) + l15) * 32 + lq * 8];
                b[i] = *(const short8*)&Bh[(wn + (i << 4) + l15) * 32 + lq * 8];
            }
            #pragma unroll
            for (int i = 0; i < 4; i++)
                #pragma unroll
                for (int j = 0; j < 4; j++)
                    acc[i][j] = __builtin_amdgcn_mfma_f32_16x16x32_bf16(a[i], b[j], acc[i][j], 0, 0, 0);
        }
    }

    #pragma unroll
    for (int i = 0; i < 4; i++) {
        int mbase = m0 + wm + (i << 4) + (lq << 2);
        #pragma unroll
        for (int j = 0; j < 4; j++) {
            int n = n0 + wn + (j << 4) + l15;
            #pragma unroll
            for (int r = 0; r < 4; r++)
                Cv[(size_t)(mbase + r) * Nn + n] = acc[i][j][r];
        }
    }
}

// ---------------- RoPE in place on planar q,k (fused: one sincos per q/k pair) ----------------
__global__ __launch_bounds__(256) void rope_planar(u16* __restrict__ qk) {
    int gid = blockIdx.x * 256 + threadIdx.x;   // (bh,t,i): 32*2048*64
    int i = gid & 63;
    int t = (gid >> 6) & 2047;
    int bh = gid >> 17;                         // 0..31
    size_t off = ((size_t)bh * 2048 + t) * 128 + 2 * i;
    u16* pq = qk + off;
    u16* pk = qk + 8388608 + off;
    float ang = (float)t * exp2f(-0.20762050596f * (float)i);
    float sv, cv;
    sincosf(ang, &sv, &cv);
    float2 q = b2f2(*(const u32*)pq);
    float2 k = b2f2(*(const u32*)pk);
    *(u32*)pq = pack2((q.x * cv - q.y * sv) * CEXP_VAL, (q.x * sv + q.y * cv) * CEXP_VAL);
    *(u32*)pk = pack2(k.x * cv - k.y * sv, k.x * sv + k.y * cv);
}

// ---------------- MFMA flash attention, 32x32x16, fixed-max, K/V double-buffered ----------------
// 256 thr = 4 waves; q-tile 128; k-tile 64; 1D grid 512 (XCD-affine, causal-balanced).
// Ping-pong K/V buffers (2 x 17536 u16 = 68.5 KB, 2 blocks/CU): after the loop-top
// barrier we issue K GLD16s + V global reads for kt+1, compute kt, then write the
// V-transpose regs. Exposed global latency per iter -> hidden behind compute.
__global__ __launch_bounds__(256, 2) void attn_mfma(const u16* __restrict__ qh, const u16* __restrict__ kh,
                                                    const u16* __restrict__ vh, u16* __restrict__ yb) {
    __shared__ __align__(16) u16 smem[35072];   // 2 buffers x (Ks 8320 + Vt 9216)
    u16* Qs = smem;                             // 32 panels * 520 = 16640 (pre-loop, inside buf0)

    const int tid = threadIdx.x;
    const int w = tid >> 6, lane = tid & 63;
    const int l31 = lane & 31, hf = lane >> 5;
    const int bid = blockIdx.x;
    const int bh = bid & 31;
    const int g = bid >> 5;
    const int qt = (g < 8) ? g : 23 - g;
    const u16* qp = qh + (size_t)bh * Tt * HDim;
    const u16* kp = kh + (size_t)bh * Tt * HDim;
    const u16* vp = vh + (size_t)bh * Tt * HDim;
    const int b = bh >> 4, h = bh & 15;
    const int qbase = qt * 128 + w * 32;

    // ---- stage Q (32 panels of 4 rows x 128) ----
    #pragma unroll
    for (int i = 0; i < 8; i++) {
        int p = w * 8 + i;
        GLD16(qp + (size_t)(qt * 128 + p * 4 + (lane >> 4)) * HDim + (lane & 15) * 8,
              &Qs[p * 520]);
    }
    __syncthreads();
    const int qrow = w * 32 + l31;
    short8 qfrag[8];
    #pragma unroll
    for (int kc = 0; kc < 8; kc++)
        qfrag[kc] = *(const short8*)&Qs[(qrow >> 2) * 520 + (qrow & 3) * 128 + kc * 16 + hf * 8];
    __syncthreads();   // all waves done reading Qs before K/V loads overwrite it

    float l_i = 0.f;   // lane-local partial (this lane's 32-k half)
    f32x16 oacc[4];
    #pragma unroll
    for (int dt = 0; dt < 4; dt++)
        #pragma unroll
        for (int r = 0; r < 16; r++) oacc[dt][r] = 0.f;

    const int vkp = tid & 31, vdc = tid >> 5;
    const int nkt = 2 * qt + 2;

    // ---- prologue: stage K/V for kt=0 into buffer 0 ----
    {
        #pragma unroll
        for (int i = 0; i < 4; i++) {
            int p = w * 4 + i;
            GLD16(kp + (size_t)(p * 4 + (lane >> 4)) * HDim + (lane & 15) * 8, &smem[p * 520]);
        }
        const u16* vsrc = vp + (size_t)(2 * vkp) * HDim + vdc * 16;
        uint4 r0a = *(const uint4*)vsrc;
        uint4 r0b = *(const uint4*)(vsrc + 8);
        uint4 r1a = *(const uint4*)(vsrc + HDim);
        uint4 r1b = *(const uint4*)(vsrc + HDim + 8);
        u16* Vt0 = smem + 8320;
        const u16* e0a = (const u16*)&r0a; const u16* e0b = (const u16*)&r0b;
        const u16* e1a = (const u16*)&r1a; const u16* e1b = (const u16*)&r1b;
        #pragma unroll
        for (int j = 0; j < 8; j++)
            *(u32*)&Vt0[(vdc * 16 + j) * 72 + vkp * 2] = (u32)e0a[j] | ((u32)e1a[j] << 16);
        #pragma unroll
        for (int j = 0; j < 8; j++)
            *(u32*)&Vt0[(vdc * 16 + 8 + j) * 72 + vkp * 2] = (u32)e0b[j] | ((u32)e1b[j] << 16);
    }

    for (int kt = 0; kt < nkt; kt++) {
        const int k0 = kt << 6;
        const int cb = kt & 1;
        u16* Ks = smem + cb * 17536;
        u16* Vt = Ks + 8320;
        __syncthreads();   // buf cb ready (its loads issued a full iteration ago)

        // issue next-iteration loads into the other buffer
        uint4 r0a, r0b, r1a, r1b;
        const bool has_next = (kt + 1 < nkt);
        u16* VtN = smem + (1 - cb) * 17536 + 8320;
        if (has_next) {
            const int kn0 = k0 + 64;
            u16* KsN = smem + (1 - cb) * 17536;
            #pragma unroll
            for (int i = 0; i < 4; i++) {
                int p = w * 4 + i;
                GLD16(kp + (size_t)(kn0 + p * 4 + (lane >> 4)) * HDim + (lane & 15) * 8,
                      &KsN[p * 520]);
            }
            const u16* vsrc = vp + (size_t)(kn0 + 2 * vkp) * HDim + vdc * 16;
            r0a = *(const uint4*)vsrc;
            r0b = *(const uint4*)(vsrc + 8);
            r1a = *(const uint4*)(vsrc + HDim);
            r1b = *(const uint4*)(vsrc + HDim + 8);
        }

        if (k0 <= qbase + 31) {      // wave-uniform causal skip
            // ---- S^T = K . Q^T : D[krow][q], q = lane&31 ----
            float pv[2][16];
            #pragma unroll
            for (int mt = 0; mt < 2; mt++) {
                f32x16 st;
                #pragma unroll
                for (int r = 0; r < 16; r++) st[r] = 0.f;
                const int krow = mt * 32 + l31;
                const u16* kbase = &Ks[(krow >> 2) * 520 + (krow & 3) * 128 + hf * 8];
                #pragma unroll
                for (int kc = 0; kc < 8; kc++) {
                    short8 ka = *(const short8*)(kbase + kc * 16);
                    st = __builtin_amdgcn_mfma_f32_32x32x16_bf16(ka, qfrag[kc], st, 0, 0, 0);
                }
                #pragma unroll
                for (int r = 0; r < 16; r++) pv[mt][r] = st[r];
            }
            // causal mask (diagonal-straddling tiles only)
            const int qg = qbase + l31;
            if (k0 + 63 > qbase) {
                #pragma unroll
                for (int mt = 0; mt < 2; mt++)
                    #pragma unroll
                    for (int r = 0; r < 16; r++) {
                        int kg = k0 + mt * 32 + (r & 3) + 8 * (r >> 2) + 4 * hf;
                        if (kg > qg) pv[mt][r] = -1e30f;
                    }
            }
            // ---- p = exp2(s), accumulate lane-local l ----
            #pragma unroll
            for (int mt = 0; mt < 2; mt++)
                #pragma unroll
                for (int r = 0; r < 16; r++) {
                    float p = exp2f(pv[mt][r]);
                    pv[mt][r] = p;
                    l_i += p;
                }

            // ---- P^T -> B-frags: pack reg pairs, one shfl_xor(32), select by half ----
            u32 pu[2][8], px[2][8];
            #pragma unroll
            for (int mt = 0; mt < 2; mt++)
                #pragma unroll
                for (int g2 = 0; g2 < 8; g2++)
                    pu[mt][g2] = pack2rz(pv[mt][2 * g2], pv[mt][2 * g2 + 1]);
            #pragma unroll
            for (int mt = 0; mt < 2; mt++)
                #pragma unroll
                for (int g2 = 0; g2 < 8; g2++)
                    px[mt][g2] = (u32)__shfl_xor((int)pu[mt][g2], 32, 64);
            short8 pb[4];
            #pragma unroll
            for (int kc = 0; kc < 4; kc++) {
                int mt = kc >> 1, g0 = (kc & 1) * 4;
                u32 f[4];
                if (hf == 0) {
                    f[0] = pu[mt][g0]; f[1] = pu[mt][g0 + 1];
                    f[2] = px[mt][g0]; f[3] = px[mt][g0 + 1];
                } else {
                    f[0] = px[mt][g0 + 2]; f[1] = px[mt][g0 + 3];
                    f[2] = pu[mt][g0 + 2]; f[3] = pu[mt][g0 + 3];
                }
                pb[kc] = *(short8*)f;
            }
            // ---- O^T += V^T . P^T : D[d][q] ----
            #pragma unroll
            for (int dt = 0; dt < 4; dt++) {
                const u16* vbase = &Vt[(dt * 32 + l31) * 72 + hf * 8];
                #pragma unroll
                for (int kc = 0; kc < 4; kc++) {
                    short8 va = *(const short8*)(vbase + kc * 16);
                    oacc[dt] = __builtin_amdgcn_mfma_f32_32x32x16_bf16(va, pb[kc], oacc[dt], 0, 0, 0);
                }
            }
        }

        // ---- write next V-transpose (after compute so the global reads are hidden) ----
        if (has_next) {
            const u16* e0a = (const u16*)&r0a; const u16* e0b = (const u16*)&r0b;
            const u16* e1a = (const u16*)&r1a; const u16* e1b = (const u16*)&r1b;
            #pragma unroll
            for (int j = 0; j < 8; j++)
                *(u32*)&VtN[(vdc * 16 + j) * 72 + vkp * 2] = (u32)e0a[j] | ((u32)e1a[j] << 16);
            #pragma unroll
            for (int j = 0; j < 8; j++)
                *(u32*)&VtN[(vdc * 16 + 8 + j) * 72 + vkp * 2] = (u32)e0b[j] | ((u32)e1b[j] << 16);
        }
    }

    // ---- epilogue: cross-half l reduce, O^T / l, transpose via LDS, store ----
    float l_tot = l_i + __shfl_xor(l_i, 32, 64);
    float linv = 1.0f / l_tot;
    #pragma unroll
    for (int dt = 0; dt < 4; dt++)
        #pragma unroll
        for (int r = 0; r < 16; r++) oacc[dt][r] *= linv;
    __syncthreads();
    u16* E = smem + w * 4384;    // per-wave [32 q][136 d]
    const int rb[8] = {0, 2, 8, 10, 16, 18, 24, 26};
    #pragma unroll
    for (int dt = 0; dt < 4; dt++)
        #pragma unroll
        for (int g2 = 0; g2 < 8; g2++) {
            int d0 = dt * 32 + rb[g2] + 4 * hf;
            *(u32*)&E[l31 * 136 + d0] = pack2(oacc[dt][2 * g2], oacc[dt][2 * g2 + 1]);
        }
    __syncthreads();
    #pragma unroll
    for (int p8 = 0; p8 < 8; p8++) {
        int ql = p8 * 4 + (lane >> 4);
        uint4 ov = *(const uint4*)&E[ql * 136 + (lane & 15) * 8];
        int t = qt * 128 + w * 32 + ql;
        *(uint4*)(yb + ((size_t)(b * Tt + t)) * Dd + h * HDim + (lane & 15) * 8) = ov;
    }
}

extern "C" void kernel_launch(void* const* d_in, const int* in_sizes, int n_in,
                              void* d_out, int out_size, void* d_ws, size_t ws_size,
                              hipStream_t stream) {
    const float* x     = (const float*)d_in[0];
    const float* w_qkv = (const float*)d_in[1];
    const float* w_out = (const float*)d_in[2];
    float* out = (float*)d_out;

    u16* ws    = (u16*)d_ws;
    u16* xb    = ws;                        //  8,388,608  x bf16 [4096][2048]
    u16* wqkvT = xb + 8388608;              // 12,582,912  w_qkv^T [6144][2048]
    u16* woutT = wqkvT + 12582912;          //  4,194,304  w_out^T [2048][2048]
    u16* qhb   = woutT + 4194304;           //  8,388,608  q planar [32][2048][128]
    u16* khb   = qhb + 8388608;             //  8,388,608
    u16* vhb   = khb + 8388608;             //  8,388,608
    u16* yb    = vhb + 8388608;             //  8,388,608  attn out [4096][2048]

    cast_f32_bf16<<<8192, 256, 0, stream>>>(x, xb, 8388608);
    transpose_cast<<<dim3(192, 64), 256, 0, stream>>>(w_qkv, wqkvT, 2048, 6144);
    transpose_cast<<<dim3(64, 64), 256, 0, stream>>>(w_out, woutT, 2048, 2048);
    gemm_qkv<<<dim3(48, 32), 256, 0, stream>>>(xb, wqkvT, qhb, 4096, 6144, 2048);
    rope_planar<<<16384, 256, 0, stream>>>(qhb);
    attn_mfma<<<512, 256, 0, stream>>>(qhb, khb, vhb, yb);
    gemm_db<<<dim3(16, 32), 256, 0, stream>>>(yb, woutT, out, 4096, 2048, 2048);
}